// Round 16
// baseline (308.398 us; speedup 1.0000x reference)
//
#include <hip/hip_runtime.h>
#include <stdint.h>

// ---- problem constants ----
#define NB 16        // batch
#define NN 4096      // nodes
#define DD 64        // feature dim (== S)
#define EE 32768     // edges (before self loops)
#define ETOT 36864   // edges + self loops
#define ROWS 65536   // B*N
#define KSPLIT 4

typedef _Float16 f16;
typedef f16   half8 __attribute__((ext_vector_type(8)));
typedef f16   f16x8 __attribute__((ext_vector_type(8)));
typedef f16   f16x4 __attribute__((ext_vector_type(4)));
typedef float f32x4 __attribute__((ext_vector_type(4)));

__device__ __forceinline__ void gload16(const f16* g, f16* l) {
  __builtin_amdgcn_global_load_lds((const __attribute__((address_space(1))) void*)g,
                                   (__attribute__((address_space(3))) void*)l, 16, 0, 0);
}

// ---------------- CSR build ----------------
__global__ __launch_bounds__(256) void k_zero2(int* a, int* b) {
  int i = blockIdx.x * 256 + threadIdx.x;
  if (i < NN) a[i] = 0;
  else if (i < 2 * NN) b[i - NN] = 0;
}

__global__ __launch_bounds__(256) void k_count(const int* __restrict__ ei, int* __restrict__ cnt) {
  int t = blockIdx.x * 256 + threadIdx.x;
  if (t >= ETOT) return;
  int d = (t < EE) ? ei[EE + t] : (t - EE);
  atomicAdd(&cnt[d], 1);
}

__global__ __launch_bounds__(256) void k_scan(const int* __restrict__ cnt, int* __restrict__ offs) {
  __shared__ int part[256];
  int t = threadIdx.x;
  int loc[16]; int s = 0;
  #pragma unroll
  for (int i = 0; i < 16; ++i) { int v = cnt[(t << 4) + i]; loc[i] = s; s += v; }
  part[t] = s;
  __syncthreads();
  int own = s;
  for (int d = 1; d < 256; d <<= 1) {
    int u = (t >= d) ? part[t - d] : 0;
    __syncthreads();
    part[t] += u;
    __syncthreads();
  }
  int base = part[t] - own;
  #pragma unroll
  for (int i = 0; i < 16; ++i) offs[(t << 4) + i] = base + loc[i];
}

__global__ __launch_bounds__(256) void k_fill(const int* __restrict__ ei, const int* __restrict__ offs,
                                              int* __restrict__ cur, int* __restrict__ esrc) {
  int t = blockIdx.x * 256 + threadIdx.x;
  if (t >= ETOT) return;
  int s, d;
  if (t < EE) { s = ei[t]; d = ei[EE + t]; } else { s = d = t - EE; }
  int p = atomicAdd(&cur[d], 1);
  esrc[offs[d] + p] = s;
}

// ---------------- seq_linear: h = in^T @ Wseq + b + in^T ----------------
__global__ __launch_bounds__(256) void k_seq(const float* __restrict__ inp, const float* __restrict__ Wseq,
                                             const float* __restrict__ bseq, float* __restrict__ h) {
  __shared__ float X[64 * 68];
  int t = threadIdx.x;
  int b = blockIdx.x >> 6, n0 = (blockIdx.x & 63) << 6;
  #pragma unroll
  for (int i = 0; i < 16; ++i) {
    int idx = t + (i << 8);
    int s = idx >> 6, nl = idx & 63;
    X[nl * 68 + s] = inp[((size_t)((b << 6) + s) << 12) + n0 + nl];
  }
  __syncthreads();
  int c = t & 63, rg = t >> 6;
  float Wc[64];
  #pragma unroll
  for (int k = 0; k < 64; ++k) Wc[k] = Wseq[(k << 6) + c];
  float bc = bseq[c];
  for (int rr = 0; rr < 16; ++rr) {
    int r = (rg << 4) + rr;
    float a = bc + X[r * 68 + c];
    #pragma unroll
    for (int k4 = 0; k4 < 16; ++k4) {
      float4 x = *(const float4*)&X[r * 68 + (k4 << 2)];
      a = fmaf(x.x, Wc[4*k4+0], a); a = fmaf(x.y, Wc[4*k4+1], a);
      a = fmaf(x.z, Wc[4*k4+2], a); a = fmaf(x.w, Wc[4*k4+3], a);
    }
    h[((size_t)(b << 12) + n0 + r) * 64 + c] = a;
  }
}

// ---------------- adjacency MFMA GEMM: single-stage, exp(relu) epilogue ----------------
__global__ __launch_bounds__(256) void k_adjmm(const f16* __restrict__ SEh, const f16* __restrict__ TEh,
                                               f16* __restrict__ A, float* __restrict__ Zpart) {
  __shared__ f16 Al[2][128 * 32];
  __shared__ f16 Bl[2][128 * 32];
  const int t = threadIdx.x, lane = t & 63, w = t >> 6;
  const int m0 = blockIdx.y << 7, j0 = blockIdx.x << 7;
  const int l15 = lane & 15, lhi = lane >> 4;
  const int wm = (w >> 1) << 6, wj = (w & 1) << 6;
  f32x4 acc[4][4] = {};
  const int c0 = (w << 6) + lane;
  const int row0 = c0 >> 2, ko0 = (c0 & 3) << 3;
  const int c1 = c0 + 256;
  const int row1 = c1 >> 2, ko1 = (c1 & 3) << 3;
  const f16* ga0 = SEh + (size_t)(m0 + row0) * 64 + ko0;
  const f16* ga1 = SEh + (size_t)(m0 + row1) * 64 + ko1;
  const f16* gb0 = TEh + (size_t)(j0 + row0) * 64 + ko0;
  const f16* gb1 = TEh + (size_t)(j0 + row1) * 64 + ko1;
  #pragma unroll
  for (int kt = 0; kt < 2; ++kt) {
    const int kof = kt << 5;
    gload16(ga0 + kof, Al[kt] + c0 * 8);
    gload16(ga1 + kof, Al[kt] + c1 * 8);
    gload16(gb0 + kof, Bl[kt] + c0 * 8);
    gload16(gb1 + kof, Bl[kt] + c1 * 8);
  }
  __syncthreads();
  #pragma unroll
  for (int kt = 0; kt < 2; ++kt) {
    half8 af[4], bf[4];
    #pragma unroll
    for (int i = 0; i < 4; ++i) {
      af[i] = *(const half8*)(Al[kt] + (wm + i * 16 + l15) * 32 + lhi * 8);
      bf[i] = *(const half8*)(Bl[kt] + (wj + i * 16 + l15) * 32 + lhi * 8);
    }
    #pragma unroll
    for (int mi = 0; mi < 4; ++mi)
      #pragma unroll
      for (int nj = 0; nj < 4; ++nj)
        acc[mi][nj] = __builtin_amdgcn_mfma_f32_16x16x32_f16(af[mi], bf[nj], acc[mi][nj], 0, 0, 0);
  }
  float rs[4][4];
  #pragma unroll
  for (int mi = 0; mi < 4; ++mi)
    #pragma unroll
    for (int r = 0; r < 4; ++r) rs[mi][r] = 0.f;
  #pragma unroll
  for (int mi = 0; mi < 4; ++mi)
    #pragma unroll
    for (int nj = 0; nj < 4; ++nj)
      #pragma unroll
      for (int r = 0; r < 4; ++r) {
        int row = m0 + wm + mi * 16 + lhi * 4 + r;
        int col = j0 + wj + nj * 16 + l15;
        float e = __expf(fmaxf(acc[mi][nj][r], 0.f));
        f16 eh = (f16)e;
        A[((size_t)row << 12) + col] = eh;
        rs[mi][r] += (float)eh;
      }
  #pragma unroll
  for (int mi = 0; mi < 4; ++mi)
    #pragma unroll
    for (int r = 0; r < 4; ++r) {
      float s = rs[mi][r];
      s += __shfl_xor(s, 1); s += __shfl_xor(s, 2);
      s += __shfl_xor(s, 4); s += __shfl_xor(s, 8);
      rs[mi][r] = s;
    }
  if (l15 == 0) {
    int p = (blockIdx.x << 1) + (w & 1);
    #pragma unroll
    for (int mi = 0; mi < 4; ++mi)
      #pragma unroll
      for (int r = 0; r < 4; ++r)
        Zpart[((size_t)p << 12) + m0 + wm + mi * 16 + lhi * 4 + r] = rs[mi][r];
  }
}

__global__ __launch_bounds__(256) void k_rowz(const float* __restrict__ Zpart, float* __restrict__ rowZ) {
  int row = blockIdx.x * 256 + threadIdx.x;
  float s = 0.f;
  #pragma unroll 8
  for (int p = 0; p < 64; ++p) s += Zpart[((size_t)p << 12) + row];
  rowZ[row] = 1.f / s;
}

// ---------------- big GEMM: BM=256 BN=256, 128x64 wave tiles (2x4), KSPLIT=4 ----------------
#define NKT 16
__global__ __launch_bounds__(512) void k_gemm8(const f16* __restrict__ A, const f16* __restrict__ BT,
                                               f16* __restrict__ Cout) {
  extern __shared__ f16 smem[];
  const int t = threadIdx.x, lane = t & 63, wid = t >> 6;
  const int wr = wid >> 2, wc = wid & 3;
  const int l15 = lane & 15, lhi = lane >> 4;
  const int h7 = l15 & 7;
  const int wgid = blockIdx.x;
  const int nid = (wgid & 7) * 32 + (wgid >> 3);
  const int z = nid >> 6, rem = nid & 63;
  const int m0 = (rem >> 2) << 8;
  const int j0 = (rem & 3) << 8;
  const size_t kbase = (size_t)z << 10;
  f16* __restrict__ Cz = Cout + ((size_t)z << 22);

  const f16* gA[4]; int lA[4];
  #pragma unroll
  for (int i = 0; i < 4; ++i) {
    int s = t + (i << 9), row = s >> 3, sl = (s & 7) ^ (row & 7);
    gA[i] = A + (size_t)(m0 + row) * 4096 + kbase + sl * 8;
    lA[i] = s * 8;
  }
  const f16* gB[4]; int lB[4];
  #pragma unroll
  for (int i = 0; i < 4; ++i) {
    int s = t + (i << 9), row = s >> 3, sl = (s & 7) ^ (row & 7);
    gB[i] = BT + (size_t)(j0 + row) * 4096 + kbase + sl * 8;
    lB[i] = 16384 + s * 8;
  }
  #define SA(buf, kt, i) gload16(gA[i] + (kt) * 64, smem + (buf) * 32768 + lA[i])
  #define SB(buf, kt, i) gload16(gB[i] + (kt) * 64, smem + (buf) * 32768 + lB[i])

  const int rbase = wr << 7;
  const int cbase = wc << 6;
  f32x4 acc[8][4] = {};

  #pragma unroll
  for (int i = 0; i < 4; ++i) SA(0, 0, i);
  #pragma unroll
  for (int i = 0; i < 4; ++i) SB(0, 0, i);
  asm volatile("s_waitcnt vmcnt(0)" ::: "memory");
  __builtin_amdgcn_sched_barrier(0);
  __builtin_amdgcn_s_barrier();
  __builtin_amdgcn_sched_barrier(0);

  for (int kt = 0; kt < NKT; ++kt) {
    const int cur = kt & 1;
    const f16* Ab = smem + cur * 32768;
    const f16* Bb = Ab + 16384;
    const bool pf = (kt + 1 < NKT);
    {
      half8 af[8], bf[4];
      #pragma unroll
      for (int mi = 0; mi < 8; ++mi) {
        int row = rbase + mi * 16 + l15;
        af[mi] = *(const half8*)(Ab + row * 64 + (lhi ^ h7) * 8);
      }
      #pragma unroll
      for (int nj = 0; nj < 4; ++nj) {
        int row = cbase + nj * 16 + l15;
        bf[nj] = *(const half8*)(Bb + row * 64 + (lhi ^ h7) * 8);
      }
      if (pf) { SA(cur ^ 1, kt + 1, 0); SA(cur ^ 1, kt + 1, 1); SA(cur ^ 1, kt + 1, 2); SA(cur ^ 1, kt + 1, 3); }
      __builtin_amdgcn_s_setprio(1);
      #pragma unroll
      for (int mi = 0; mi < 8; ++mi)
        #pragma unroll
        for (int nj = 0; nj < 4; ++nj)
          acc[mi][nj] = __builtin_amdgcn_mfma_f32_16x16x32_f16(af[mi], bf[nj], acc[mi][nj], 0, 0, 0);
      __builtin_amdgcn_s_setprio(0);
    }
    {
      half8 af[8], bf[4];
      #pragma unroll
      for (int mi = 0; mi < 8; ++mi) {
        int row = rbase + mi * 16 + l15;
        af[mi] = *(const half8*)(Ab + row * 64 + ((4 + lhi) ^ h7) * 8);
      }
      #pragma unroll
      for (int nj = 0; nj < 4; ++nj) {
        int row = cbase + nj * 16 + l15;
        bf[nj] = *(const half8*)(Bb + row * 64 + ((4 + lhi) ^ h7) * 8);
      }
      if (pf) { SB(cur ^ 1, kt + 1, 0); SB(cur ^ 1, kt + 1, 1); SB(cur ^ 1, kt + 1, 2); SB(cur ^ 1, kt + 1, 3); }
      __builtin_amdgcn_s_setprio(1);
      #pragma unroll
      for (int mi = 0; mi < 8; ++mi)
        #pragma unroll
        for (int nj = 0; nj < 4; ++nj)
          acc[mi][nj] = __builtin_amdgcn_mfma_f32_16x16x32_f16(af[mi], bf[nj], acc[mi][nj], 0, 0, 0);
      __builtin_amdgcn_s_setprio(0);
    }
    if (pf) {
      asm volatile("s_waitcnt vmcnt(0)" ::: "memory");
      __builtin_amdgcn_sched_barrier(0);
      __builtin_amdgcn_s_barrier();
      __builtin_amdgcn_sched_barrier(0);
    }
  }
  #undef SA
  #undef SB
  #pragma unroll
  for (int mi = 0; mi < 8; ++mi)
    #pragma unroll
    for (int nj = 0; nj < 4; ++nj)
      #pragma unroll
      for (int r = 0; r < 4; ++r) {
        int row = m0 + rbase + mi * 16 + (lhi << 2) + r;
        int col = j0 + cbase + nj * 16 + l15;
        Cz[(size_t)row * 1024 + col] = (f16)acc[mi][nj][r];
      }
}

// ---------------- fused prep: Wgh1, Wgh2, W0h, SE cast, TE cast ----------------
template<int H, int NP>
__device__ __forceinline__ void wprep_body(const float* __restrict__ Wg, const float* __restrict__ asrc,
                                           const float* __restrict__ adst, const float* __restrict__ Wl,
                                           f16* __restrict__ Wgh, int bid, int t) {
  const int WL0 = H * 64 + 16;
  for (int i = bid * 256 + t; i < NP * 64; i += 16 * 256) {
    int j = i >> 6, k = i & 63;
    float v;
    if (j < H * 64) {
      v = Wg[(size_t)k * (H * 64) + j];
    } else if (j < H * 64 + 2 * H) {
      int cc = j - H * 64, hh = cc >> 1;
      const float* a = ((cc & 1) ? adst : asrc) + (hh << 6);
      const float* wrow = Wg + (size_t)k * (H * 64) + (hh << 6);
      float s = 0.f;
      #pragma unroll 16
      for (int c = 0; c < 64; ++c) s = fmaf(wrow[c], a[c], s);
      v = s;
    } else if (j >= WL0 && j < WL0 + 64) {
      v = Wl[(k << 6) + (j - WL0)];
    } else v = 0.f;
    Wgh[(size_t)j * 64 + k] = (f16)v;
  }
}

__global__ __launch_bounds__(256) void k_allprep(
    const float* __restrict__ Wg1, const float* __restrict__ as1, const float* __restrict__ ad1,
    const float* __restrict__ Wl1, f16* __restrict__ Wgh1,
    const float* __restrict__ Wg2, const float* __restrict__ as2, const float* __restrict__ ad2,
    const float* __restrict__ Wl2, f16* __restrict__ Wgh2,
    const float* __restrict__ Wl0, const float* __restrict__ Wo, f16* __restrict__ W0h,
    const float* __restrict__ SE, const float* __restrict__ TE,
    f16* __restrict__ SEh, f16* __restrict__ TEh) {
  __shared__ float X[64 * 65];
  int bid = blockIdx.x, t = threadIdx.x;
  if (bid < 16) { wprep_body<3, 272>(Wg1, as1, ad1, Wl1, Wgh1, bid, t); return; }
  if (bid < 32) { wprep_body<1, 144>(Wg2, as2, ad2, Wl2, Wgh2, bid - 16, t); return; }
  if (bid < 40) {
    for (int i = (bid - 32) * 256 + t; i < 128 * 64; i += 8 * 256) {
      int j = i >> 6, k = i & 63;
      float v = (j < 64) ? Wl0[(k << 6) + j] : Wo[(k << 6) + (j - 64)];
      W0h[(size_t)j * 64 + k] = (f16)v;
    }
    return;
  }
  if (bid < 296) {                     // SE cast
    int i = ((bid - 40) * 256 + t) * 4;
    float4 v = *(const float4*)(SE + i);
    f16 o[4] = {(f16)v.x, (f16)v.y, (f16)v.z, (f16)v.w};
    *(uint64_t*)(SEh + i) = *(uint64_t*)o;
    return;
  }
  // TE transpose-cast
  int j0 = (bid - 296) << 6;
  #pragma unroll
  for (int i = 0; i < 16; ++i) {
    int idx = t + (i << 8);
    int k = idx >> 6, jl = idx & 63;
    X[jl * 65 + k] = TE[((size_t)k << 12) + j0 + jl];
  }
  __syncthreads();
  int jl = t >> 2, kg = t & 3;
  f16 o[16];
  #pragma unroll
  for (int i = 0; i < 16; ++i) o[i] = (f16)X[jl * 65 + (kg << 4) + i];
  f16* dst = TEh + ((size_t)(j0 + jl) << 6) + (kg << 4);
  *(uint64_t*)(dst + 0) = *(uint64_t*)(o + 0);
  *(uint64_t*)(dst + 4) = *(uint64_t*)(o + 4);
  *(uint64_t*)(dst + 8) = *(uint64_t*)(o + 8);
  *(uint64_t*)(dst + 12) = *(uint64_t*)(o + 12);
}

// ---------------- xp = h @ Wg via MFMA + als4/ald4 + HWlT ----------------
template<int H, int NP>
__global__ __launch_bounds__(256) void k_xpmm(const float* __restrict__ h, const f16* __restrict__ Wgh,
                                              f16* __restrict__ xp, float* __restrict__ als4,
                                              float* __restrict__ ald4, f16* __restrict__ HWlT) {
  const int WL0 = H * 64 + 16, JW0 = WL0 / 16, NT = NP / 16;
  __shared__ f16 Ah[64 * 72];
  __shared__ f16 Bh[NP * 72];
  __shared__ f16 stage[64 * 72];
  const int t = threadIdx.x, lane = t & 63, w = t >> 6;
  const size_t r0 = (size_t)blockIdx.x * 64;
  const int b = (int)(r0 >> 12), n0 = (int)(r0 & 4095);
  #pragma unroll
  for (int i = 0; i < 4; ++i) {
    int idx = t + (i << 8);
    int row = idx >> 4, k4 = (idx & 15) << 2;
    float4 v = *(const float4*)&h[(r0 + row) * 64 + k4];
    f16 o[4] = {(f16)v.x, (f16)v.y, (f16)v.z, (f16)v.w};
    *(uint64_t*)&Ah[row * 72 + k4] = *(uint64_t*)o;
  }
  for (int i = t; i < NP * 16; i += 256) {
    int row = i >> 4, k4 = (i & 15) << 2;
    *(uint64_t*)&Bh[row * 72 + k4] = *(const uint64_t*)&Wgh[(size_t)row * 64 + k4];
  }
  __syncthreads();
  const int l15 = lane & 15, lhi = lane >> 4;
  f32x4 acc[NT] = {};
  #pragma unroll
  for (int kk = 0; kk < 2; ++kk) {
    half8 af = *(const half8*)&Ah[(w * 16 + l15) * 72 + kk * 32 + lhi * 8];
    #pragma unroll
    for (int j = 0; j < NT; ++j) {
      half8 bf = *(const half8*)&Bh[(j * 16 + l15) * 72 + kk * 32 + lhi * 8];
      acc[j] = __builtin_amdgcn_mfma_f32_16x16x32_f16(af, bf, acc[j], 0, 0, 0);
    }
  }
  const int rl = w * 16 + lhi * 4;
  #pragma unroll
  for (int j = 0; j < NT; ++j) {
    int col = j * 16 + l15;
    if (j * 16 + 15 < H * 64) {
      #pragma unroll
      for (int r = 0; r < 4; ++r) {
        if (H == 3) xp[(r0 + rl + r) * 256 + ((col & 63) << 2) + (col >> 6)] = (f16)acc[j][r];
        else        xp[(r0 + rl + r) * 64 + col] = (f16)acc[j][r];
      }
    } else if (j < JW0) {
      int cc = col - H * 64;
      if (cc >= 0 && cc < 2 * H) {
        int hh = cc >> 1;
        #pragma unroll
        for (int r = 0; r < 4; ++r) {
          if (cc & 1) ald4[(r0 + rl + r) * 4 + hh] = acc[j][r];
          else        als4[(r0 + rl + r) * 4 + hh] = acc[j][r];
        }
      }
    } else {
      int e = col - WL0;
      f16 o[4] = {(f16)acc[j][0], (f16)acc[j][1], (f16)acc[j][2], (f16)acc[j][3]};
      *(uint64_t*)&stage[e * 72 + rl] = *(uint64_t*)o;
    }
  }
  __syncthreads();
  {
    int e = t >> 2, seg = (t & 3) << 4;
    float4 v0 = *(const float4*)&stage[e * 72 + seg];
    float4 v1 = *(const float4*)&stage[e * 72 + seg + 8];
    f16* dst = HWlT + (((size_t)((b << 6) + e)) << 12) + n0 + seg;
    *(float4*)dst = v0;
    *(float4*)(dst + 8) = v1;
  }
}

// ---------------- layer-0 prep: h @ [Wl0|Wo] -> HWlT + orig ----------------
__global__ __launch_bounds__(256) void k_prep0(const float* __restrict__ h, const f16* __restrict__ W0h,
                                               f16* __restrict__ HWlT, f16* __restrict__ orig) {
  __shared__ f16 Ah[64 * 72];
  __shared__ f16 Bh[128 * 72];
  __shared__ f16 stage[64 * 72];
  const int t = threadIdx.x, lane = t & 63, w = t >> 6;
  const size_t r0 = (size_t)blockIdx.x * 64;
  const int b = (int)(r0 >> 12), n0 = (int)(r0 & 4095);
  #pragma unroll
  for (int i = 0; i < 4; ++i) {
    int idx = t + (i << 8);
    int row = idx >> 4, k4 = (idx & 15) << 2;
    float4 v = *(const float4*)&h[(r0 + row) * 64 + k4];
    f16 o[4] = {(f16)v.x, (f16)v.y, (f16)v.z, (f16)v.w};
    *(uint64_t*)&Ah[row * 72 + k4] = *(uint64_t*)o;
  }
  for (int i = t; i < 128 * 16; i += 256) {
    int row = i >> 4, k4 = (i & 15) << 2;
    *(uint64_t*)&Bh[row * 72 + k4] = *(const uint64_t*)&W0h[(size_t)row * 64 + k4];
  }
  __syncthreads();
  const int l15 = lane & 15, lhi = lane >> 4;
  f32x4 acc[8] = {};
  #pragma unroll
  for (int kk = 0; kk < 2; ++kk) {
    half8 af = *(const half8*)&Ah[(w * 16 + l15) * 72 + kk * 32 + lhi * 8];
    #pragma unroll
    for (int j = 0; j < 8; ++j) {
      half8 bf = *(const half8*)&Bh[(j * 16 + l15) * 72 + kk * 32 + lhi * 8];
      acc[j] = __builtin_amdgcn_mfma_f32_16x16x32_f16(af, bf, acc[j], 0, 0, 0);
    }
  }
  const int rl = w * 16 + lhi * 4;
  #pragma unroll
  for (int j = 0; j < 8; ++j) {
    int col = j * 16 + l15;
    if (j < 4) {
      f16 o[4] = {(f16)acc[j][0], (f16)acc[j][1], (f16)acc[j][2], (f16)acc[j][3]};
      *(uint64_t*)&stage[col * 72 + rl] = *(uint64_t*)o;
    } else {
      #pragma unroll
      for (int r = 0; r < 4; ++r)
        orig[(r0 + rl + r) * 64 + (col - 64)] = (f16)acc[j][r];
    }
  }
  __syncthreads();
  {
    int e = t >> 2, seg = (t & 3) << 4;
    float4 v0 = *(const float4*)&stage[e * 72 + seg];
    float4 v1 = *(const float4*)&stage[e * 72 + seg + 8];
    f16* dst = HWlT + (((size_t)((b << 6) + e)) << 12) + n0 + seg;
    *(float4*)dst = v0;
    *(float4*)(dst + 8) = v1;
  }
}

// ---------------- GAT aggregation + fused weights + fused gate combine ----------------
// Weights computed inline (shift-free: w = exp(min(ev,60)); ratio w/z is shift-invariant).
// XCD-pinned batches; scalarized gather base via readfirstlane.
template<int H, int ACT>   // ACT 0: leaky 0.01, 1: relu
__global__ __launch_bounds__(256) void k_aggc(const f16* __restrict__ xp, const float* __restrict__ als4,
                                              const float* __restrict__ ald4,
                                              const int* __restrict__ offs, const int* __restrict__ cnt,
                                              const int* __restrict__ esrc, const float* __restrict__ bg,
                                              const float* __restrict__ h, const f16* __restrict__ gp,
                                              const float* __restrict__ rowZ, const float* __restrict__ bl,
                                              float* __restrict__ hout) {
  const int WST = (H == 3) ? 4 : 1;
  __shared__ float wbuf[4][64 * WST];
  __shared__ int   sbuf[4][64];
  int t = threadIdx.x, lane = t & 63, wv = t >> 6;
  int blk = blockIdx.x;
  int b = ((blk & 7) << 1) | ((blk >> 3) & 1);
  int n = ((blk >> 4) << 2) + wv;
  size_t rbase = (size_t)b << 12;
  int o = offs[n], c = cnt[n];
  // wave-uniform ald
  float ad0 = ald4[(rbase + n) * 4 + 0];
  float ad1 = (H == 3) ? ald4[(rbase + n) * 4 + 1] : 0.f;
  float ad2 = (H == 3) ? ald4[(rbase + n) * 4 + 2] : 0.f;
  const f16* xpb = xp + (rbase << (H == 3 ? 8 : 6));
  float z[H], acc[H];
  #pragma unroll
  for (int hh = 0; hh < H; ++hh) { z[hh] = 0.f; acc[hh] = 0.f; }
  for (int e0 = 0; e0 < c; e0 += 64) {
    int ce = min(64, c - e0);
    if (lane < ce) {
      int sl = esrc[o + e0 + lane];
      sbuf[wv][lane] = sl;
      if (H == 3) {
        float4 a4 = *(const float4*)&als4[(rbase + sl) * 4];
        float ev0 = a4.x + ad0; ev0 = ev0 > 0.f ? ev0 : 0.2f * ev0;
        float ev1 = a4.y + ad1; ev1 = ev1 > 0.f ? ev1 : 0.2f * ev1;
        float ev2 = a4.z + ad2; ev2 = ev2 > 0.f ? ev2 : 0.2f * ev2;
        float4 w4;
        w4.x = __expf(fminf(ev0, 60.f));
        w4.y = __expf(fminf(ev1, 60.f));
        w4.z = __expf(fminf(ev2, 60.f));
        w4.w = 0.f;
        *(float4*)&wbuf[wv][lane * 4] = w4;
      } else {
        float ev = als4[(rbase + sl) * 4] + ad0;
        ev = ev > 0.f ? ev : 0.2f * ev;
        wbuf[wv][lane] = __expf(fminf(ev, 60.f));
      }
    }
    #pragma unroll 4
    for (int e = 0; e < ce; ++e) {
      int s = __builtin_amdgcn_readfirstlane(sbuf[wv][e]);
      if (H == 3) {
        float4 w4 = *(const float4*)&wbuf[wv][e * 4];
        f16x4 q = *(const f16x4*)(xpb + ((size_t)s << 8) + (lane << 2));
        z[0] += w4.x; acc[0] = fmaf(w4.x, (float)q[0], acc[0]);
        z[1] += w4.y; acc[1] = fmaf(w4.y, (float)q[1], acc[1]);
        z[2] += w4.z; acc[2] = fmaf(w4.z, (float)q[2], acc[2]);
      } else {
        float wv_ = wbuf[wv][e];
        float xv = (float)xpb[((size_t)s << 6) + lane];
        z[0] += wv_; acc[0] = fmaf(wv_, xv, acc[0]);
      }
    }
  }
  float r = 0.f;
  #pragma unroll
  for (int hh = 0; hh < H; ++hh) r += acc[hh] / z[hh];
  float cv = r * (1.f / H) + bg[lane];
  size_t ga = ((size_t)n << 10) + (b << 6) + lane;
  float zi = rowZ[n];
  float gs = 0.f;
  #pragma unroll
  for (int p = 0; p < KSPLIT; ++p) gs += (float)gp[ga + (size_t)p * (4096 * 1024)];
  float g = 1.f / (1.f + __expf(-(gs * zi + bl[lane])));
  size_t ridx = ((rbase + n) << 6) + lane;
  float hv = h[ridx];
  float act = ACT ? fmaxf(cv, 0.f) : (cv > 0.f ? cv : 0.01f * cv);
  hout[ridx] = act * g + hv * (1.f - g);
}

// ---------------- layer-0 combine: pure elementwise ----------------
__global__ __launch_bounds__(256) void k_comb0e(const float* __restrict__ h, const f16* __restrict__ gp,
                                                const float* __restrict__ rowZ, const f16* __restrict__ orig,
                                                const float* __restrict__ bl, const float* __restrict__ bo,
                                                float* __restrict__ hout) {
  for (size_t i4 = (size_t)blockIdx.x * 256 + threadIdx.x; i4 < (size_t)ROWS * 16; i4 += (size_t)2048 * 256) {
    size_t i = i4 * 4;
    int d = (int)(i & 63), n = (int)((i >> 6) & 4095), b = (int)(i >> 18);
    size_t ga = ((size_t)n << 10) + (b << 6) + d;
    float zi = rowZ[n];
    float gs[4] = {0.f, 0.f, 0.f, 0.f};
    #pragma unroll
    for (int p = 0; p < KSPLIT; ++p) {
      f16x4 gq = *(const f16x4*)&gp[ga + (size_t)p * (4096 * 1024)];
      gs[0] += (float)gq[0]; gs[1] += (float)gq[1]; gs[2] += (float)gq[2]; gs[3] += (float)gq[3];
    }
    f16x4 og = *(const f16x4*)&orig[i];
    float4 hv = *(const float4*)&h[i];
    float4 o;
    float* op = &o.x;
    const float* hp = &hv.x;
    #pragma unroll
    for (int r = 0; r < 4; ++r) {
      float g = 1.f / (1.f + __expf(-(gs[r] * zi + bl[d + r])));
      float orv = (float)og[r] + bo[d + r];
      op[r] = tanhf(hp[r]) * g + orv * (1.f - g);
    }
    *(float4*)&hout[i] = o;
  }
}

// ---------------- host launch ----------------
extern "C" void kernel_launch(void* const* d_in, const int* in_sizes, int n_in,
                              void* d_out, int out_size, void* d_ws, size_t ws_size,
                              hipStream_t stream) {
  (void)in_sizes; (void)n_in; (void)out_size; (void)ws_size;
  const float* inp  = (const float*)d_in[0];
  const int*   ei   = (const int*)d_in[1];
  const float* Wseq = (const float*)d_in[2];
  const float* bseq = (const float*)d_in[3];
  const float* SE   = (const float*)d_in[4];
  const float* TE   = (const float*)d_in[5];
  const float* Wg[3]   = {(const float*)d_in[6],  (const float*)d_in[12], (const float*)d_in[18]};
  const float* asrc[3] = {(const float*)d_in[7],  (const float*)d_in[13], (const float*)d_in[19]};
  const float* adst[3] = {(const float*)d_in[8],  (const float*)d_in[14], (const float*)d_in[20]};
  const float* bgp[3]  = {(const float*)d_in[9],  (const float*)d_in[15], (const float*)d_in[21]};
  const float* Wl[3]   = {(const float*)d_in[10], (const float*)d_in[16], (const float*)d_in[22]};
  const float* bl[3]   = {(const float*)d_in[11], (const float*)d_in[17], (const float*)d_in[23]};
  const float* Wo = (const float*)d_in[24];
  const float* bo = (const float*)d_in[25];
  float* out = (float*)d_out;

  uint8_t* ws = (uint8_t*)d_ws;
  size_t o = 0;
  auto nxt = [&](size_t sz) { void* p = ws + o; o += (sz + 255) & ~(size_t)255; return p; };
  f16*   Af   = (f16*)  nxt((size_t)NN * NN * sizeof(f16));            // 32 MB
  f16*   HWlT = (f16*)  nxt((size_t)1024 * NN * sizeof(f16));          // 8 MB
  float* h    = (float*)nxt((size_t)ROWS * 64 * 4);                    // 16 MB
  f16*   gp   = (f16*)  nxt((size_t)KSPLIT * NN * 1024 * sizeof(f16)); // 32 MB (4 partials)
  f16*   xp   = (f16*)  nxt((size_t)ROWS * 256 * sizeof(f16));         // 32 MB (H=3 interleaved)
  f16*   orig = (f16*)  nxt((size_t)ROWS * 64 * sizeof(f16));          // 8 MB
  float* als4 = (float*)nxt((size_t)ROWS * 4 * 4);                     // 1 MB
  float* ald4 = (float*)nxt((size_t)ROWS * 4 * 4);                     // 1 MB
  float* rowZ = (float*)nxt((size_t)NN * 4);
  float* Zpart= (float*)nxt((size_t)64 * NN * 4);                      // 1 MB
  f16*   SEh  = (f16*)  nxt((size_t)NN * 64 * sizeof(f16));
  f16*   TEh  = (f16*)  nxt((size_t)NN * 64 * sizeof(f16));
  f16*   Wgh1 = (f16*)  nxt((size_t)288 * 64 * sizeof(f16));
  f16*   Wgh2 = (f16*)  nxt((size_t)144 * 64 * sizeof(f16));
  f16*   W0h  = (f16*)  nxt((size_t)128 * 64 * sizeof(f16));
  int*   cnt  = (int*)  nxt((size_t)NN * 4);
  int*   curp = (int*)  nxt((size_t)NN * 4);
  int*   offs = (int*)  nxt((size_t)NN * 4);
  int*   esrc = (int*)  nxt((size_t)ETOT * 4);

  static bool attr_set = false;
  if (!attr_set) {
    hipFuncSetAttribute((const void*)k_gemm8, hipFuncAttributeMaxDynamicSharedMemorySize, 131072);
    attr_set = true;
  }

  dim3 blk(256);
  // CSR build + independent prep (incl. SE/TE casts)
  k_zero2<<<32, blk, 0, stream>>>(cnt, curp);
  k_count<<<144, blk, 0, stream>>>(ei, cnt);
  k_scan<<<1, blk, 0, stream>>>(cnt, offs);
  k_fill<<<144, blk, 0, stream>>>(ei, offs, curp, esrc);
  k_allprep<<<360, blk, 0, stream>>>(Wg[1], asrc[1], adst[1], Wl[1], Wgh1,
                                     Wg[2], asrc[2], adst[2], Wl[2], Wgh2,
                                     Wl[0], Wo, W0h, SE, TE, SEh, TEh);
  // h0 + adjacency
  k_seq<<<1024, blk, 0, stream>>>(inp, Wseq, bseq, h);
  k_adjmm<<<dim3(32, 32), blk, 0, stream>>>(SEh, TEh, Af, Zpart);
  k_rowz<<<16, blk, 0, stream>>>(Zpart, rowZ);
  // ---- layer 0 ----
  k_prep0<<<1024, blk, 0, stream>>>(h, W0h, HWlT, orig);
  k_gemm8<<<256, 512, 131072, stream>>>(Af, HWlT, gp);
  k_comb0e<<<2048, blk, 0, stream>>>(h, gp, rowZ, orig, bl[0], bo, h);
  // ---- layer 1 ----
  k_xpmm<3, 272><<<1024, blk, 0, stream>>>(h, Wgh1, xp, als4, ald4, HWlT);
  k_gemm8<<<256, 512, 131072, stream>>>(Af, HWlT, gp);
  k_aggc<3, 0><<<16384, blk, 0, stream>>>(xp, als4, ald4, offs, cnt, esrc, bgp[1], h, gp, rowZ, bl[1], h);
  // ---- layer 2 ----
  k_xpmm<1, 144><<<1024, blk, 0, stream>>>(h, Wgh2, xp, als4, ald4, HWlT);
  k_gemm8<<<256, 512, 131072, stream>>>(Af, HWlT, gp);
  k_aggc<1, 1><<<16384, blk, 0, stream>>>(xp, als4, ald4, offs, cnt, esrc, bgp[2], h, gp, rowZ, bl[2], out);
}

// Round 17
// 282.257 us; speedup vs baseline: 1.0926x; 1.0926x over previous
//
#include <hip/hip_runtime.h>
#include <stdint.h>

// ---- problem constants ----
#define NB 16        // batch
#define NN 4096      // nodes
#define DD 64        // feature dim (== S)
#define EE 32768     // edges (before self loops)
#define ETOT 36864   // edges + self loops
#define ROWS 65536   // B*N
#define KSPLIT 4

typedef _Float16 f16;
typedef f16   half8 __attribute__((ext_vector_type(8)));
typedef f16   f16x8 __attribute__((ext_vector_type(8)));
typedef f16   f16x4 __attribute__((ext_vector_type(4)));
typedef float f32x4 __attribute__((ext_vector_type(4)));

__device__ __forceinline__ void gload16(const f16* g, f16* l) {
  __builtin_amdgcn_global_load_lds((const __attribute__((address_space(1))) void*)g,
                                   (__attribute__((address_space(3))) void*)l, 16, 0, 0);
}

// ---------------- CSR build ----------------
__global__ __launch_bounds__(256) void k_zero2(int* a, int* b) {
  int i = blockIdx.x * 256 + threadIdx.x;
  if (i < NN) a[i] = 0;
  else if (i < 2 * NN) b[i - NN] = 0;
}

__global__ __launch_bounds__(256) void k_count(const int* __restrict__ ei, int* __restrict__ cnt) {
  int t = blockIdx.x * 256 + threadIdx.x;
  if (t >= ETOT) return;
  int d = (t < EE) ? ei[EE + t] : (t - EE);
  atomicAdd(&cnt[d], 1);
}

__global__ __launch_bounds__(256) void k_scan(const int* __restrict__ cnt, int* __restrict__ offs) {
  __shared__ int part[256];
  int t = threadIdx.x;
  int loc[16]; int s = 0;
  #pragma unroll
  for (int i = 0; i < 16; ++i) { int v = cnt[(t << 4) + i]; loc[i] = s; s += v; }
  part[t] = s;
  __syncthreads();
  int own = s;
  for (int d = 1; d < 256; d <<= 1) {
    int u = (t >= d) ? part[t - d] : 0;
    __syncthreads();
    part[t] += u;
    __syncthreads();
  }
  int base = part[t] - own;
  #pragma unroll
  for (int i = 0; i < 16; ++i) offs[(t << 4) + i] = base + loc[i];
}

__global__ __launch_bounds__(256) void k_fill(const int* __restrict__ ei, const int* __restrict__ offs,
                                              int* __restrict__ cur, int* __restrict__ esrc,
                                              int* __restrict__ edst) {
  int t = blockIdx.x * 256 + threadIdx.x;
  if (t >= ETOT) return;
  int s, d;
  if (t < EE) { s = ei[t]; d = ei[EE + t]; } else { s = d = t - EE; }
  int p = atomicAdd(&cur[d], 1);
  esrc[offs[d] + p] = s;
  edst[offs[d] + p] = d;
}

// ---------------- seq_linear: h = in^T @ Wseq + b + in^T ----------------
__global__ __launch_bounds__(256) void k_seq(const float* __restrict__ inp, const float* __restrict__ Wseq,
                                             const float* __restrict__ bseq, float* __restrict__ h) {
  __shared__ float X[64 * 68];
  int t = threadIdx.x;
  int b = blockIdx.x >> 6, n0 = (blockIdx.x & 63) << 6;
  #pragma unroll
  for (int i = 0; i < 16; ++i) {
    int idx = t + (i << 8);
    int s = idx >> 6, nl = idx & 63;
    X[nl * 68 + s] = inp[((size_t)((b << 6) + s) << 12) + n0 + nl];
  }
  __syncthreads();
  int c = t & 63, rg = t >> 6;
  float Wc[64];
  #pragma unroll
  for (int k = 0; k < 64; ++k) Wc[k] = Wseq[(k << 6) + c];
  float bc = bseq[c];
  for (int rr = 0; rr < 16; ++rr) {
    int r = (rg << 4) + rr;
    float a = bc + X[r * 68 + c];
    #pragma unroll
    for (int k4 = 0; k4 < 16; ++k4) {
      float4 x = *(const float4*)&X[r * 68 + (k4 << 2)];
      a = fmaf(x.x, Wc[4*k4+0], a); a = fmaf(x.y, Wc[4*k4+1], a);
      a = fmaf(x.z, Wc[4*k4+2], a); a = fmaf(x.w, Wc[4*k4+3], a);
    }
    h[((size_t)(b << 12) + n0 + r) * 64 + c] = a;
  }
}

// ---------------- adjacency MFMA GEMM: single-stage, exp(relu) epilogue ----------------
__global__ __launch_bounds__(256) void k_adjmm(const f16* __restrict__ SEh, const f16* __restrict__ TEh,
                                               f16* __restrict__ A, float* __restrict__ Zpart) {
  __shared__ f16 Al[2][128 * 32];
  __shared__ f16 Bl[2][128 * 32];
  const int t = threadIdx.x, lane = t & 63, w = t >> 6;
  const int m0 = blockIdx.y << 7, j0 = blockIdx.x << 7;
  const int l15 = lane & 15, lhi = lane >> 4;
  const int wm = (w >> 1) << 6, wj = (w & 1) << 6;
  f32x4 acc[4][4] = {};
  const int c0 = (w << 6) + lane;
  const int row0 = c0 >> 2, ko0 = (c0 & 3) << 3;
  const int c1 = c0 + 256;
  const int row1 = c1 >> 2, ko1 = (c1 & 3) << 3;
  const f16* ga0 = SEh + (size_t)(m0 + row0) * 64 + ko0;
  const f16* ga1 = SEh + (size_t)(m0 + row1) * 64 + ko1;
  const f16* gb0 = TEh + (size_t)(j0 + row0) * 64 + ko0;
  const f16* gb1 = TEh + (size_t)(j0 + row1) * 64 + ko1;
  #pragma unroll
  for (int kt = 0; kt < 2; ++kt) {
    const int kof = kt << 5;
    gload16(ga0 + kof, Al[kt] + c0 * 8);
    gload16(ga1 + kof, Al[kt] + c1 * 8);
    gload16(gb0 + kof, Bl[kt] + c0 * 8);
    gload16(gb1 + kof, Bl[kt] + c1 * 8);
  }
  __syncthreads();
  #pragma unroll
  for (int kt = 0; kt < 2; ++kt) {
    half8 af[4], bf[4];
    #pragma unroll
    for (int i = 0; i < 4; ++i) {
      af[i] = *(const half8*)(Al[kt] + (wm + i * 16 + l15) * 32 + lhi * 8);
      bf[i] = *(const half8*)(Bl[kt] + (wj + i * 16 + l15) * 32 + lhi * 8);
    }
    #pragma unroll
    for (int mi = 0; mi < 4; ++mi)
      #pragma unroll
      for (int nj = 0; nj < 4; ++nj)
        acc[mi][nj] = __builtin_amdgcn_mfma_f32_16x16x32_f16(af[mi], bf[nj], acc[mi][nj], 0, 0, 0);
  }
  float rs[4][4];
  #pragma unroll
  for (int mi = 0; mi < 4; ++mi)
    #pragma unroll
    for (int r = 0; r < 4; ++r) rs[mi][r] = 0.f;
  #pragma unroll
  for (int mi = 0; mi < 4; ++mi)
    #pragma unroll
    for (int nj = 0; nj < 4; ++nj)
      #pragma unroll
      for (int r = 0; r < 4; ++r) {
        int row = m0 + wm + mi * 16 + lhi * 4 + r;
        int col = j0 + wj + nj * 16 + l15;
        float e = __expf(fmaxf(acc[mi][nj][r], 0.f));
        f16 eh = (f16)e;
        A[((size_t)row << 12) + col] = eh;
        rs[mi][r] += (float)eh;
      }
  #pragma unroll
  for (int mi = 0; mi < 4; ++mi)
    #pragma unroll
    for (int r = 0; r < 4; ++r) {
      float s = rs[mi][r];
      s += __shfl_xor(s, 1); s += __shfl_xor(s, 2);
      s += __shfl_xor(s, 4); s += __shfl_xor(s, 8);
      rs[mi][r] = s;
    }
  if (l15 == 0) {
    int p = (blockIdx.x << 1) + (w & 1);
    #pragma unroll
    for (int mi = 0; mi < 4; ++mi)
      #pragma unroll
      for (int r = 0; r < 4; ++r)
        Zpart[((size_t)p << 12) + m0 + wm + mi * 16 + lhi * 4 + r] = rs[mi][r];
  }
}

__global__ __launch_bounds__(256) void k_rowz(const float* __restrict__ Zpart, float* __restrict__ rowZ) {
  int row = blockIdx.x * 256 + threadIdx.x;
  float s = 0.f;
  #pragma unroll 8
  for (int p = 0; p < 64; ++p) s += Zpart[((size_t)p << 12) + row];
  rowZ[row] = 1.f / s;
}

// ---------------- big GEMM: BM=256 BN=256, 128x64 wave tiles (2x4), KSPLIT=4 ----------------
#define NKT 16
__global__ __launch_bounds__(512) void k_gemm8(const f16* __restrict__ A, const f16* __restrict__ BT,
                                               f16* __restrict__ Cout) {
  extern __shared__ f16 smem[];
  const int t = threadIdx.x, lane = t & 63, wid = t >> 6;
  const int wr = wid >> 2, wc = wid & 3;
  const int l15 = lane & 15, lhi = lane >> 4;
  const int h7 = l15 & 7;
  const int wgid = blockIdx.x;
  const int nid = (wgid & 7) * 32 + (wgid >> 3);
  const int z = nid >> 6, rem = nid & 63;
  const int m0 = (rem >> 2) << 8;
  const int j0 = (rem & 3) << 8;
  const size_t kbase = (size_t)z << 10;
  f16* __restrict__ Cz = Cout + ((size_t)z << 22);

  const f16* gA[4]; int lA[4];
  #pragma unroll
  for (int i = 0; i < 4; ++i) {
    int s = t + (i << 9), row = s >> 3, sl = (s & 7) ^ (row & 7);
    gA[i] = A + (size_t)(m0 + row) * 4096 + kbase + sl * 8;
    lA[i] = s * 8;
  }
  const f16* gB[4]; int lB[4];
  #pragma unroll
  for (int i = 0; i < 4; ++i) {
    int s = t + (i << 9), row = s >> 3, sl = (s & 7) ^ (row & 7);
    gB[i] = BT + (size_t)(j0 + row) * 4096 + kbase + sl * 8;
    lB[i] = 16384 + s * 8;
  }
  #define SA(buf, kt, i) gload16(gA[i] + (kt) * 64, smem + (buf) * 32768 + lA[i])
  #define SB(buf, kt, i) gload16(gB[i] + (kt) * 64, smem + (buf) * 32768 + lB[i])

  const int rbase = wr << 7;
  const int cbase = wc << 6;
  f32x4 acc[8][4] = {};

  #pragma unroll
  for (int i = 0; i < 4; ++i) SA(0, 0, i);
  #pragma unroll
  for (int i = 0; i < 4; ++i) SB(0, 0, i);
  asm volatile("s_waitcnt vmcnt(0)" ::: "memory");
  __builtin_amdgcn_sched_barrier(0);
  __builtin_amdgcn_s_barrier();
  __builtin_amdgcn_sched_barrier(0);

  for (int kt = 0; kt < NKT; ++kt) {
    const int cur = kt & 1;
    const f16* Ab = smem + cur * 32768;
    const f16* Bb = Ab + 16384;
    const bool pf = (kt + 1 < NKT);
    {
      half8 af[8], bf[4];
      #pragma unroll
      for (int mi = 0; mi < 8; ++mi) {
        int row = rbase + mi * 16 + l15;
        af[mi] = *(const half8*)(Ab + row * 64 + (lhi ^ h7) * 8);
      }
      #pragma unroll
      for (int nj = 0; nj < 4; ++nj) {
        int row = cbase + nj * 16 + l15;
        bf[nj] = *(const half8*)(Bb + row * 64 + (lhi ^ h7) * 8);
      }
      if (pf) { SA(cur ^ 1, kt + 1, 0); SA(cur ^ 1, kt + 1, 1); SA(cur ^ 1, kt + 1, 2); SA(cur ^ 1, kt + 1, 3); }
      __builtin_amdgcn_s_setprio(1);
      #pragma unroll
      for (int mi = 0; mi < 8; ++mi)
        #pragma unroll
        for (int nj = 0; nj < 4; ++nj)
          acc[mi][nj] = __builtin_amdgcn_mfma_f32_16x16x32_f16(af[mi], bf[nj], acc[mi][nj], 0, 0, 0);
      __builtin_amdgcn_s_setprio(0);
    }
    {
      half8 af[8], bf[4];
      #pragma unroll
      for (int mi = 0; mi < 8; ++mi) {
        int row = rbase + mi * 16 + l15;
        af[mi] = *(const half8*)(Ab + row * 64 + ((4 + lhi) ^ h7) * 8);
      }
      #pragma unroll
      for (int nj = 0; nj < 4; ++nj) {
        int row = cbase + nj * 16 + l15;
        bf[nj] = *(const half8*)(Bb + row * 64 + ((4 + lhi) ^ h7) * 8);
      }
      if (pf) { SB(cur ^ 1, kt + 1, 0); SB(cur ^ 1, kt + 1, 1); SB(cur ^ 1, kt + 1, 2); SB(cur ^ 1, kt + 1, 3); }
      __builtin_amdgcn_s_setprio(1);
      #pragma unroll
      for (int mi = 0; mi < 8; ++mi)
        #pragma unroll
        for (int nj = 0; nj < 4; ++nj)
          acc[mi][nj] = __builtin_amdgcn_mfma_f32_16x16x32_f16(af[mi], bf[nj], acc[mi][nj], 0, 0, 0);
      __builtin_amdgcn_s_setprio(0);
    }
    if (pf) {
      asm volatile("s_waitcnt vmcnt(0)" ::: "memory");
      __builtin_amdgcn_sched_barrier(0);
      __builtin_amdgcn_s_barrier();
      __builtin_amdgcn_sched_barrier(0);
    }
  }
  #undef SA
  #undef SB
  #pragma unroll
  for (int mi = 0; mi < 8; ++mi)
    #pragma unroll
    for (int nj = 0; nj < 4; ++nj)
      #pragma unroll
      for (int r = 0; r < 4; ++r) {
        int row = m0 + rbase + mi * 16 + (lhi << 2) + r;
        int col = j0 + cbase + nj * 16 + l15;
        Cz[(size_t)row * 1024 + col] = (f16)acc[mi][nj][r];
      }
}

// ---------------- fused prep: Wgh1, Wgh2, W0h, SE cast, TE cast ----------------
template<int H, int NP>
__device__ __forceinline__ void wprep_body(const float* __restrict__ Wg, const float* __restrict__ asrc,
                                           const float* __restrict__ adst, const float* __restrict__ Wl,
                                           f16* __restrict__ Wgh, int bid, int t) {
  const int WL0 = H * 64 + 16;
  for (int i = bid * 256 + t; i < NP * 64; i += 16 * 256) {
    int j = i >> 6, k = i & 63;
    float v;
    if (j < H * 64) {
      v = Wg[(size_t)k * (H * 64) + j];
    } else if (j < H * 64 + 2 * H) {
      int cc = j - H * 64, hh = cc >> 1;
      const float* a = ((cc & 1) ? adst : asrc) + (hh << 6);
      const float* wrow = Wg + (size_t)k * (H * 64) + (hh << 6);
      float s = 0.f;
      #pragma unroll 16
      for (int c = 0; c < 64; ++c) s = fmaf(wrow[c], a[c], s);
      v = s;
    } else if (j >= WL0 && j < WL0 + 64) {
      v = Wl[(k << 6) + (j - WL0)];
    } else v = 0.f;
    Wgh[(size_t)j * 64 + k] = (f16)v;
  }
}

__global__ __launch_bounds__(256) void k_allprep(
    const float* __restrict__ Wg1, const float* __restrict__ as1, const float* __restrict__ ad1,
    const float* __restrict__ Wl1, f16* __restrict__ Wgh1,
    const float* __restrict__ Wg2, const float* __restrict__ as2, const float* __restrict__ ad2,
    const float* __restrict__ Wl2, f16* __restrict__ Wgh2,
    const float* __restrict__ Wl0, const float* __restrict__ Wo, f16* __restrict__ W0h,
    const float* __restrict__ SE, const float* __restrict__ TE,
    f16* __restrict__ SEh, f16* __restrict__ TEh) {
  __shared__ float X[64 * 65];
  int bid = blockIdx.x, t = threadIdx.x;
  if (bid < 16) { wprep_body<3, 272>(Wg1, as1, ad1, Wl1, Wgh1, bid, t); return; }
  if (bid < 32) { wprep_body<1, 144>(Wg2, as2, ad2, Wl2, Wgh2, bid - 16, t); return; }
  if (bid < 40) {
    for (int i = (bid - 32) * 256 + t; i < 128 * 64; i += 8 * 256) {
      int j = i >> 6, k = i & 63;
      float v = (j < 64) ? Wl0[(k << 6) + j] : Wo[(k << 6) + (j - 64)];
      W0h[(size_t)j * 64 + k] = (f16)v;
    }
    return;
  }
  if (bid < 296) {                     // SE cast
    int i = ((bid - 40) * 256 + t) * 4;
    float4 v = *(const float4*)(SE + i);
    f16 o[4] = {(f16)v.x, (f16)v.y, (f16)v.z, (f16)v.w};
    *(uint64_t*)(SEh + i) = *(uint64_t*)o;
    return;
  }
  // TE transpose-cast
  int j0 = (bid - 296) << 6;
  #pragma unroll
  for (int i = 0; i < 16; ++i) {
    int idx = t + (i << 8);
    int k = idx >> 6, jl = idx & 63;
    X[jl * 65 + k] = TE[((size_t)k << 12) + j0 + jl];
  }
  __syncthreads();
  int jl = t >> 2, kg = t & 3;
  f16 o[16];
  #pragma unroll
  for (int i = 0; i < 16; ++i) o[i] = (f16)X[jl * 65 + (kg << 4) + i];
  f16* dst = TEh + ((size_t)(j0 + jl) << 6) + (kg << 4);
  *(uint64_t*)(dst + 0) = *(uint64_t*)(o + 0);
  *(uint64_t*)(dst + 4) = *(uint64_t*)(o + 4);
  *(uint64_t*)(dst + 8) = *(uint64_t*)(o + 8);
  *(uint64_t*)(dst + 12) = *(uint64_t*)(o + 12);
}

// ---------------- xp = h @ Wg via MFMA + als4/ald4 + HWlT ----------------
template<int H, int NP>
__global__ __launch_bounds__(256) void k_xpmm(const float* __restrict__ h, const f16* __restrict__ Wgh,
                                              f16* __restrict__ xp, float* __restrict__ als4,
                                              float* __restrict__ ald4, f16* __restrict__ HWlT) {
  const int WL0 = H * 64 + 16, JW0 = WL0 / 16, NT = NP / 16;
  __shared__ f16 Ah[64 * 72];
  __shared__ f16 Bh[NP * 72];
  __shared__ f16 stage[64 * 72];
  const int t = threadIdx.x, lane = t & 63, w = t >> 6;
  const size_t r0 = (size_t)blockIdx.x * 64;
  const int b = (int)(r0 >> 12), n0 = (int)(r0 & 4095);
  #pragma unroll
  for (int i = 0; i < 4; ++i) {
    int idx = t + (i << 8);
    int row = idx >> 4, k4 = (idx & 15) << 2;
    float4 v = *(const float4*)&h[(r0 + row) * 64 + k4];
    f16 o[4] = {(f16)v.x, (f16)v.y, (f16)v.z, (f16)v.w};
    *(uint64_t*)&Ah[row * 72 + k4] = *(uint64_t*)o;
  }
  for (int i = t; i < NP * 16; i += 256) {
    int row = i >> 4, k4 = (i & 15) << 2;
    *(uint64_t*)&Bh[row * 72 + k4] = *(const uint64_t*)&Wgh[(size_t)row * 64 + k4];
  }
  __syncthreads();
  const int l15 = lane & 15, lhi = lane >> 4;
  f32x4 acc[NT] = {};
  #pragma unroll
  for (int kk = 0; kk < 2; ++kk) {
    half8 af = *(const half8*)&Ah[(w * 16 + l15) * 72 + kk * 32 + lhi * 8];
    #pragma unroll
    for (int j = 0; j < NT; ++j) {
      half8 bf = *(const half8*)&Bh[(j * 16 + l15) * 72 + kk * 32 + lhi * 8];
      acc[j] = __builtin_amdgcn_mfma_f32_16x16x32_f16(af, bf, acc[j], 0, 0, 0);
    }
  }
  const int rl = w * 16 + lhi * 4;
  #pragma unroll
  for (int j = 0; j < NT; ++j) {
    int col = j * 16 + l15;
    if (j * 16 + 15 < H * 64) {
      #pragma unroll
      for (int r = 0; r < 4; ++r) {
        if (H == 3) xp[(r0 + rl + r) * 256 + ((col & 63) << 2) + (col >> 6)] = (f16)acc[j][r];
        else        xp[(r0 + rl + r) * 64 + col] = (f16)acc[j][r];
      }
    } else if (j < JW0) {
      int cc = col - H * 64;
      if (cc >= 0 && cc < 2 * H) {
        int hh = cc >> 1;
        #pragma unroll
        for (int r = 0; r < 4; ++r) {
          if (cc & 1) ald4[(r0 + rl + r) * 4 + hh] = acc[j][r];
          else        als4[(r0 + rl + r) * 4 + hh] = acc[j][r];
        }
      }
    } else {
      int e = col - WL0;
      f16 o[4] = {(f16)acc[j][0], (f16)acc[j][1], (f16)acc[j][2], (f16)acc[j][3]};
      *(uint64_t*)&stage[e * 72 + rl] = *(uint64_t*)o;
    }
  }
  __syncthreads();
  {
    int e = t >> 2, seg = (t & 3) << 4;
    float4 v0 = *(const float4*)&stage[e * 72 + seg];
    float4 v1 = *(const float4*)&stage[e * 72 + seg + 8];
    f16* dst = HWlT + (((size_t)((b << 6) + e)) << 12) + n0 + seg;
    *(float4*)dst = v0;
    *(float4*)(dst + 8) = v1;
  }
}

// ---------------- layer-0 prep: h @ [Wl0|Wo] -> HWlT + orig ----------------
__global__ __launch_bounds__(256) void k_prep0(const float* __restrict__ h, const f16* __restrict__ W0h,
                                               f16* __restrict__ HWlT, f16* __restrict__ orig) {
  __shared__ f16 Ah[64 * 72];
  __shared__ f16 Bh[128 * 72];
  __shared__ f16 stage[64 * 72];
  const int t = threadIdx.x, lane = t & 63, w = t >> 6;
  const size_t r0 = (size_t)blockIdx.x * 64;
  const int b = (int)(r0 >> 12), n0 = (int)(r0 & 4095);
  #pragma unroll
  for (int i = 0; i < 4; ++i) {
    int idx = t + (i << 8);
    int row = idx >> 4, k4 = (idx & 15) << 2;
    float4 v = *(const float4*)&h[(r0 + row) * 64 + k4];
    f16 o[4] = {(f16)v.x, (f16)v.y, (f16)v.z, (f16)v.w};
    *(uint64_t*)&Ah[row * 72 + k4] = *(uint64_t*)o;
  }
  for (int i = t; i < 128 * 16; i += 256) {
    int row = i >> 4, k4 = (i & 15) << 2;
    *(uint64_t*)&Bh[row * 72 + k4] = *(const uint64_t*)&W0h[(size_t)row * 64 + k4];
  }
  __syncthreads();
  const int l15 = lane & 15, lhi = lane >> 4;
  f32x4 acc[8] = {};
  #pragma unroll
  for (int kk = 0; kk < 2; ++kk) {
    half8 af = *(const half8*)&Ah[(w * 16 + l15) * 72 + kk * 32 + lhi * 8];
    #pragma unroll
    for (int j = 0; j < 8; ++j) {
      half8 bf = *(const half8*)&Bh[(j * 16 + l15) * 72 + kk * 32 + lhi * 8];
      acc[j] = __builtin_amdgcn_mfma_f32_16x16x32_f16(af, bf, acc[j], 0, 0, 0);
    }
  }
  const int rl = w * 16 + lhi * 4;
  #pragma unroll
  for (int j = 0; j < 8; ++j) {
    int col = j * 16 + l15;
    if (j < 4) {
      f16 o[4] = {(f16)acc[j][0], (f16)acc[j][1], (f16)acc[j][2], (f16)acc[j][3]};
      *(uint64_t*)&stage[col * 72 + rl] = *(uint64_t*)o;
    } else {
      #pragma unroll
      for (int r = 0; r < 4; ++r)
        orig[(r0 + rl + r) * 64 + (col - 64)] = (f16)acc[j][r];
    }
  }
  __syncthreads();
  {
    int e = t >> 2, seg = (t & 3) << 4;
    float4 v0 = *(const float4*)&stage[e * 72 + seg];
    float4 v1 = *(const float4*)&stage[e * 72 + seg + 8];
    f16* dst = HWlT + (((size_t)((b << 6) + e)) << 12) + n0 + seg;
    *(float4*)dst = v0;
    *(float4*)(dst + 8) = v1;
  }
}

// ---------------- edge weights, shift-free: w = exp(min(leaky(als+ald), 60)) ----------------
template<int H>
__global__ __launch_bounds__(256) void k_wts(const float* __restrict__ als4, const float* __restrict__ ald4,
                                             const int* __restrict__ esrc, const int* __restrict__ edst,
                                             float* __restrict__ wts) {
  const int WST = (H == 3) ? 4 : 1;
  int t = threadIdx.x, lane = t & 63, w = t >> 6;
  int gw = blockIdx.x * 4 + w;
  int b = gw & 15;
  int p = ((gw >> 4) << 6) + lane;
  size_t rbase = (size_t)b << 12;
  int s = esrc[p], n = edst[p];
  float4 a4 = *(const float4*)&als4[(rbase + s) * 4];
  float4 d4 = *(const float4*)&ald4[(rbase + n) * 4];
  const float* ap = &a4.x;
  const float* dp = &d4.x;
  float* dst = wts + ((size_t)b * ETOT + p) * WST;
  #pragma unroll
  for (int h = 0; h < H; ++h) {
    float ev = ap[h] + dp[h];
    ev = ev > 0.f ? ev : 0.2f * ev;
    dst[h] = __expf(fminf(ev, 60.f));
  }
}

// ---------------- GAT aggregation + fused gate combine; paired batches per wave ----------------
// XCD pinning: blk&7 -> XCD owns batches {2x, 2x+1}; one wave handles node n for BOTH,
// sharing edge list + loop control. Grid 8192.
template<int H, int ACT>   // ACT 0: leaky 0.01, 1: relu
__global__ __launch_bounds__(256) void k_aggc(const f16* __restrict__ xp, const float* __restrict__ wts,
                                              const int* __restrict__ offs, const int* __restrict__ cnt,
                                              const int* __restrict__ esrc, const float* __restrict__ bg,
                                              const float* __restrict__ h, const f16* __restrict__ gp,
                                              const float* __restrict__ rowZ, const float* __restrict__ bl,
                                              float* __restrict__ hout) {
  const int WST = (H == 3) ? 4 : 1;
  __shared__ float wbuf[4][64 * WST * 2];
  __shared__ int   sbuf[4][64];
  int t = threadIdx.x, lane = t & 63, wv = t >> 6;
  int blk = blockIdx.x;
  int b0 = (blk & 7) << 1, b1 = b0 | 1;
  int n = ((blk >> 3) << 2) + wv;
  size_t rb0 = (size_t)b0 << 12, rb1 = (size_t)b1 << 12;
  int o = offs[n], c = cnt[n];
  const float* ws0 = wts + ((size_t)b0 * ETOT + o) * WST;
  const float* ws1 = wts + ((size_t)b1 * ETOT + o) * WST;
  const int xsh = (H == 3) ? 8 : 6;
  const f16* xp0 = xp + (rb0 << xsh);
  const f16* xp1 = xp + (rb1 << xsh);
  float z0[H], a0[H], z1[H], a1[H];
  #pragma unroll
  for (int hh = 0; hh < H; ++hh) { z0[hh] = 0.f; a0[hh] = 0.f; z1[hh] = 0.f; a1[hh] = 0.f; }
  for (int e0 = 0; e0 < c; e0 += 64) {
    int ce = min(64, c - e0);
    if (lane < ce) {
      sbuf[wv][lane] = esrc[o + e0 + lane];
      if (H == 3) {
        *(float4*)&wbuf[wv][lane * 8]     = *(const float4*)&ws0[(size_t)(e0 + lane) * 4];
        *(float4*)&wbuf[wv][lane * 8 + 4] = *(const float4*)&ws1[(size_t)(e0 + lane) * 4];
      } else {
        wbuf[wv][lane * 2]     = ws0[e0 + lane];
        wbuf[wv][lane * 2 + 1] = ws1[e0 + lane];
      }
    }
    #pragma unroll 4
    for (int e = 0; e < ce; ++e) {
      int s = sbuf[wv][e];
      if (H == 3) {
        float4 w40 = *(const float4*)&wbuf[wv][e * 8];
        float4 w41 = *(const float4*)&wbuf[wv][e * 8 + 4];
        f16x4 q0 = *(const f16x4*)(xp0 + ((size_t)s << 8) + (lane << 2));
        f16x4 q1 = *(const f16x4*)(xp1 + ((size_t)s << 8) + (lane << 2));
        z0[0] += w40.x; a0[0] = fmaf(w40.x, (float)q0[0], a0[0]);
        z0[1] += w40.y; a0[1] = fmaf(w40.y, (float)q0[1], a0[1]);
        z0[2] += w40.z; a0[2] = fmaf(w40.z, (float)q0[2], a0[2]);
        z1[0] += w41.x; a1[0] = fmaf(w41.x, (float)q1[0], a1[0]);
        z1[1] += w41.y; a1[1] = fmaf(w41.y, (float)q1[1], a1[1]);
        z1[2] += w41.z; a1[2] = fmaf(w41.z, (float)q1[2], a1[2]);
      } else {
        float w0 = wbuf[wv][e * 2], w1 = wbuf[wv][e * 2 + 1];
        float x0 = (float)xp0[((size_t)s << 6) + lane];
        float x1 = (float)xp1[((size_t)s << 6) + lane];
        z0[0] += w0; a0[0] = fmaf(w0, x0, a0[0]);
        z1[0] += w1; a1[0] = fmaf(w1, x1, a1[0]);
      }
    }
  }
  float bgl = bg[lane], bll = bl[lane], zi = rowZ[n];
  #pragma unroll
  for (int pb = 0; pb < 2; ++pb) {
    int b = pb ? b1 : b0;
    size_t rb = pb ? rb1 : rb0;
    float* zz = pb ? z1 : z0;
    float* aa = pb ? a1 : a0;
    float r = 0.f;
    #pragma unroll
    for (int hh = 0; hh < H; ++hh) r += aa[hh] / zz[hh];
    float cv = r * (1.f / H) + bgl;
    size_t ga = ((size_t)n << 10) + (b << 6) + lane;
    float gs = 0.f;
    #pragma unroll
    for (int p = 0; p < KSPLIT; ++p) gs += (float)gp[ga + (size_t)p * (4096 * 1024)];
    float g = 1.f / (1.f + __expf(-(gs * zi + bll)));
    size_t ridx = ((rb + n) << 6) + lane;
    float hv = h[ridx];
    float act = ACT ? fmaxf(cv, 0.f) : (cv > 0.f ? cv : 0.01f * cv);
    hout[ridx] = act * g + hv * (1.f - g);
  }
}

// ---------------- layer-0 combine: pure elementwise ----------------
__global__ __launch_bounds__(256) void k_comb0e(const float* __restrict__ h, const f16* __restrict__ gp,
                                                const float* __restrict__ rowZ, const f16* __restrict__ orig,
                                                const float* __restrict__ bl, const float* __restrict__ bo,
                                                float* __restrict__ hout) {
  for (size_t i4 = (size_t)blockIdx.x * 256 + threadIdx.x; i4 < (size_t)ROWS * 16; i4 += (size_t)2048 * 256) {
    size_t i = i4 * 4;
    int d = (int)(i & 63), n = (int)((i >> 6) & 4095), b = (int)(i >> 18);
    size_t ga = ((size_t)n << 10) + (b << 6) + d;
    float zi = rowZ[n];
    float gs[4] = {0.f, 0.f, 0.f, 0.f};
    #pragma unroll
    for (int p = 0; p < KSPLIT; ++p) {
      f16x4 gq = *(const f16x4*)&gp[ga + (size_t)p * (4096 * 1024)];
      gs[0] += (float)gq[0]; gs[1] += (float)gq[1]; gs[2] += (float)gq[2]; gs[3] += (float)gq[3];
    }
    f16x4 og = *(const f16x4*)&orig[i];
    float4 hv = *(const float4*)&h[i];
    float4 o;
    float* op = &o.x;
    const float* hp = &hv.x;
    #pragma unroll
    for (int r = 0; r < 4; ++r) {
      float g = 1.f / (1.f + __expf(-(gs[r] * zi + bl[d + r])));
      float orv = (float)og[r] + bo[d + r];
      op[r] = tanhf(hp[r]) * g + orv * (1.f - g);
    }
    *(float4*)&hout[i] = o;
  }
}

// ---------------- host launch ----------------
extern "C" void kernel_launch(void* const* d_in, const int* in_sizes, int n_in,
                              void* d_out, int out_size, void* d_ws, size_t ws_size,
                              hipStream_t stream) {
  (void)in_sizes; (void)n_in; (void)out_size; (void)ws_size;
  const float* inp  = (const float*)d_in[0];
  const int*   ei   = (const int*)d_in[1];
  const float* Wseq = (const float*)d_in[2];
  const float* bseq = (const float*)d_in[3];
  const float* SE   = (const float*)d_in[4];
  const float* TE   = (const float*)d_in[5];
  const float* Wg[3]   = {(const float*)d_in[6],  (const float*)d_in[12], (const float*)d_in[18]};
  const float* asrc[3] = {(const float*)d_in[7],  (const float*)d_in[13], (const float*)d_in[19]};
  const float* adst[3] = {(const float*)d_in[8],  (const float*)d_in[14], (const float*)d_in[20]};
  const float* bgp[3]  = {(const float*)d_in[9],  (const float*)d_in[15], (const float*)d_in[21]};
  const float* Wl[3]   = {(const float*)d_in[10], (const float*)d_in[16], (const float*)d_in[22]};
  const float* bl[3]   = {(const float*)d_in[11], (const float*)d_in[17], (const float*)d_in[23]};
  const float* Wo = (const float*)d_in[24];
  const float* bo = (const float*)d_in[25];
  float* out = (float*)d_out;

  uint8_t* ws = (uint8_t*)d_ws;
  size_t o = 0;
  auto nxt = [&](size_t sz) { void* p = ws + o; o += (sz + 255) & ~(size_t)255; return p; };
  f16*   Af   = (f16*)  nxt((size_t)NN * NN * sizeof(f16));            // 32 MB
  f16*   HWlT = (f16*)  nxt((size_t)1024 * NN * sizeof(f16));          // 8 MB
  float* h    = (float*)nxt((size_t)ROWS * 64 * 4);                    // 16 MB
  f16*   gp   = (f16*)  nxt((size_t)KSPLIT * NN * 1024 * sizeof(f16)); // 32 MB (4 partials)
  f16*   xp   = (f16*)  nxt((size_t)ROWS * 256 * sizeof(f16));         // 32 MB (H=3 interleaved)
  f16*   orig = (f16*)  nxt((size_t)ROWS * 64 * sizeof(f16));          // 8 MB
  float* als4 = (float*)nxt((size_t)ROWS * 4 * 4);                     // 1 MB
  float* ald4 = (float*)nxt((size_t)ROWS * 4 * 4);                     // 1 MB
  float* rowZ = (float*)nxt((size_t)NN * 4);
  float* Zpart= (float*)nxt((size_t)64 * NN * 4);                      // 1 MB
  f16*   SEh  = (f16*)  nxt((size_t)NN * 64 * sizeof(f16));
  f16*   TEh  = (f16*)  nxt((size_t)NN * 64 * sizeof(f16));
  f16*   Wgh1 = (f16*)  nxt((size_t)288 * 64 * sizeof(f16));
  f16*   Wgh2 = (f16*)  nxt((size_t)144 * 64 * sizeof(f16));
  f16*   W0h  = (f16*)  nxt((size_t)128 * 64 * sizeof(f16));
  float* wts  = (float*)nxt((size_t)NB * ETOT * 4 * 4);                // 9.4 MB (stride-4)
  int*   cnt  = (int*)  nxt((size_t)NN * 4);
  int*   curp = (int*)  nxt((size_t)NN * 4);
  int*   offs = (int*)  nxt((size_t)NN * 4);
  int*   esrc = (int*)  nxt((size_t)ETOT * 4);
  int*   edst = (int*)  nxt((size_t)ETOT * 4);

  static bool attr_set = false;
  if (!attr_set) {
    hipFuncSetAttribute((const void*)k_gemm8, hipFuncAttributeMaxDynamicSharedMemorySize, 131072);
    attr_set = true;
  }

  dim3 blk(256);
  // CSR build + independent prep (incl. SE/TE casts)
  k_zero2<<<32, blk, 0, stream>>>(cnt, curp);
  k_count<<<144, blk, 0, stream>>>(ei, cnt);
  k_scan<<<1, blk, 0, stream>>>(cnt, offs);
  k_fill<<<144, blk, 0, stream>>>(ei, offs, curp, esrc, edst);
  k_allprep<<<360, blk, 0, stream>>>(Wg[1], asrc[1], adst[1], Wl[1], Wgh1,
                                     Wg[2], asrc[2], adst[2], Wl[2], Wgh2,
                                     Wl[0], Wo, W0h, SE, TE, SEh, TEh);
  // h0 + adjacency
  k_seq<<<1024, blk, 0, stream>>>(inp, Wseq, bseq, h);
  k_adjmm<<<dim3(32, 32), blk, 0, stream>>>(SEh, TEh, Af, Zpart);
  k_rowz<<<16, blk, 0, stream>>>(Zpart, rowZ);
  // ---- layer 0 ----
  k_prep0<<<1024, blk, 0, stream>>>(h, W0h, HWlT, orig);
  k_gemm8<<<256, 512, 131072, stream>>>(Af, HWlT, gp);
  k_comb0e<<<2048, blk, 0, stream>>>(h, gp, rowZ, orig, bl[0], bo, h);
  // ---- layer 1 ----
  k_xpmm<3, 272><<<1024, blk, 0, stream>>>(h, Wgh1, xp, als4, ald4, HWlT);
  k_wts<3><<<2304, blk, 0, stream>>>(als4, ald4, esrc, edst, wts);
  k_gemm8<<<256, 512, 131072, stream>>>(Af, HWlT, gp);
  k_aggc<3, 0><<<8192, blk, 0, stream>>>(xp, wts, offs, cnt, esrc, bgp[1], h, gp, rowZ, bl[1], h);
  // ---- layer 2 ----
  k_xpmm<1, 144><<<1024, blk, 0, stream>>>(h, Wgh2, xp, als4, ald4, HWlT);
  k_wts<1><<<2304, blk, 0, stream>>>(als4, ald4, esrc, edst, wts);
  k_gemm8<<<256, 512, 131072, stream>>>(Af, HWlT, gp);
  k_aggc<1, 1><<<8192, blk, 0, stream>>>(xp, wts, offs, cnt, esrc, bgp[2], h, gp, rowZ, bl[2], out);
}